// Round 1
// baseline (883.028 us; speedup 1.0000x reference)
//
#include <hip/hip_runtime.h>
#include <hip/hip_bf16.h>

#define N_ENTITY 64368
#define N_REL 40
#define DIM 128
#define N_BASES 8
#define N_EDGES 500000
#define BATCH 64
#define SEED_LEN 32

// ---------------------------------------------------------------------------
// Kernel 1: edge scatter. One wave (64 lanes) per edge; lane l handles dims
// 2l, 2l+1 as a float2. 8 independent basis-row loads issued back-to-back to
// keep 8 vmcnt loads in flight. Hardware fp32 atomics (unsafeAtomicAdd).
// ---------------------------------------------------------------------------
__global__ __launch_bounds__(256) void edge_scatter(
    const int* __restrict__ esrc, const int* __restrict__ edst,
    const int* __restrict__ etype, const float* __restrict__ basis,
    const float* __restrict__ att, float* __restrict__ agg,
    float* __restrict__ deg)
{
    int wid  = (int)((blockIdx.x * blockDim.x + threadIdx.x) >> 6);
    int lane = threadIdx.x & 63;
    if (wid >= N_EDGES) return;

    int src = esrc[wid];
    int dst = edst[wid];
    int ty  = etype[wid];

    const float* ar = att + ty * N_BASES;
    float c0 = ar[0], c1 = ar[1], c2 = ar[2], c3 = ar[3];
    float c4 = ar[4], c5 = ar[5], c6 = ar[6], c7 = ar[7];

    const size_t bstride = (size_t)N_ENTITY * DIM;
    const float* base = basis + (size_t)src * DIM + lane * 2;

    float2 v0 = *(const float2*)(base + 0 * bstride);
    float2 v1 = *(const float2*)(base + 1 * bstride);
    float2 v2 = *(const float2*)(base + 2 * bstride);
    float2 v3 = *(const float2*)(base + 3 * bstride);
    float2 v4 = *(const float2*)(base + 4 * bstride);
    float2 v5 = *(const float2*)(base + 5 * bstride);
    float2 v6 = *(const float2*)(base + 6 * bstride);
    float2 v7 = *(const float2*)(base + 7 * bstride);

    float mx = c0 * v0.x + c1 * v1.x + c2 * v2.x + c3 * v3.x
             + c4 * v4.x + c5 * v5.x + c6 * v6.x + c7 * v7.x;
    float my = c0 * v0.y + c1 * v1.y + c2 * v2.y + c3 * v3.y
             + c4 * v4.y + c5 * v5.y + c6 * v6.y + c7 * v7.y;

    float* dp = agg + (size_t)dst * DIM + lane * 2;
    unsafeAtomicAdd(dp + 0, mx);
    unsafeAtomicAdd(dp + 1, my);
    if (lane == 0) unsafeAtomicAdd(deg + dst, 1.0f);
}

// ---------------------------------------------------------------------------
// Kernel 2: finalize nodes in place: agg = agg/max(deg,1) + root + bias
// ---------------------------------------------------------------------------
__global__ __launch_bounds__(256) void finalize4(
    float4* __restrict__ agg, const float* __restrict__ deg,
    const float4* __restrict__ root, const float4* __restrict__ bias)
{
    int i = blockIdx.x * 256 + threadIdx.x;
    if (i >= N_ENTITY * (DIM / 4)) return;
    int n  = i >> 5;          // DIM/4 == 32 float4 per node
    int d4 = i & 31;
    float inv = 1.0f / fmaxf(deg[n], 1.0f);
    float4 a = agg[i];
    float4 r = root[i];
    float4 b = bias[d4];
    a.x = a.x * inv + r.x + b.x;
    a.y = a.y * inv + r.y + b.y;
    a.z = a.z * inv + r.z + b.z;
    a.w = a.w * inv + r.w + b.w;
    agg[i] = a;
}

// ---------------------------------------------------------------------------
// Kernel 3: attention pooling, one block per batch element.
// e[s] = sum_j tanh(H[s]·A[:,j]) * b[j]; softmax over s; u = attn @ H
// ---------------------------------------------------------------------------
#define HS_STR 132   // pad 128 -> 132 to spread the 8-way same-bank broadcast

__global__ __launch_bounds__(256) void attn_pool(
    const int* __restrict__ seed_ids, const float* __restrict__ nodes,
    const float* __restrict__ A, const float* __restrict__ Bv,
    float* __restrict__ u)
{
    __shared__ float Hs[SEED_LEN * HS_STR];
    __shared__ float part[SEED_LEN][9];
    __shared__ float attw[SEED_LEN];

    int b = blockIdx.x, tid = threadIdx.x;

    for (int i = tid; i < SEED_LEN * DIM; i += 256) {
        int s = i >> 7, d = i & 127;
        int nid = seed_ids[b * SEED_LEN + s];
        Hs[s * HS_STR + d] = nodes[(size_t)nid * DIM + d];
    }
    __syncthreads();

    int s = tid >> 3;    // 0..31
    int g = tid & 7;     // 0..7
    float pe = 0.0f;
    for (int j = g; j < DIM; j += 8) {
        float acc = 0.0f;
        for (int d = 0; d < DIM; ++d)
            acc += Hs[s * HS_STR + d] * A[d * DIM + j];
        pe += tanhf(acc) * Bv[j];
    }
    part[s][g] = pe;
    __syncthreads();

    if (tid < SEED_LEN) {
        float e = 0.0f;
        for (int k = 0; k < 8; ++k) e += part[tid][k];
        attw[tid] = e;
    }
    __syncthreads();

    if (tid == 0) {
        float mx = -1e30f;
        for (int k = 0; k < SEED_LEN; ++k) mx = fmaxf(mx, attw[k]);
        float ssum = 0.0f;
        for (int k = 0; k < SEED_LEN; ++k) {
            float v = expf(attw[k] - mx);
            attw[k] = v;
            ssum += v;
        }
        float inv = 1.0f / ssum;
        for (int k = 0; k < SEED_LEN; ++k) attw[k] *= inv;
    }
    __syncthreads();

    if (tid < DIM) {
        float acc = 0.0f;
        for (int k = 0; k < SEED_LEN; ++k)
            acc += attw[k] * Hs[k * HS_STR + tid];
        u[b * DIM + tid] = acc;
    }
}

// ---------------------------------------------------------------------------
// Kernel 4: scores[b, n] = u[b]·nodes[n] + out_bias[n]
// Block: 256 threads, tile = 64 batches x 32 nodes, transposed LDS layouts
// (strides 65/33 keep both staging writes and main-loop reads conflict-free).
// Each thread owns a 2x4 (b x n) register tile.
// ---------------------------------------------------------------------------
__global__ __launch_bounds__(256) void scores_kernel(
    const float* __restrict__ nodes, const float* __restrict__ u,
    const float* __restrict__ out_bias, float* __restrict__ out)
{
    __shared__ float Ul[DIM * 65];   // [d][b], stride 65
    __shared__ float Nl[DIM * 33];   // [d][n], stride 33

    int tid = threadIdx.x;
    int n0  = blockIdx.x * 32;

    for (int i = tid; i < BATCH * DIM; i += 256) {
        int b = i >> 7, d = i & 127;
        Ul[d * 65 + b] = u[i];
    }
    for (int i = tid; i < 32 * DIM; i += 256) {
        int n = i >> 7, d = i & 127;
        int gn = n0 + n;
        Nl[d * 33 + n] = (gn < N_ENTITY) ? nodes[(size_t)gn * DIM + d] : 0.0f;
    }
    __syncthreads();

    int nx = tid & 7;     // node group: n = nx*4 + j
    int by = tid >> 3;    // batch group: b = by*2 + i
    float acc[2][4] = {{0.f, 0.f, 0.f, 0.f}, {0.f, 0.f, 0.f, 0.f}};

    for (int d = 0; d < DIM; ++d) {
        float ub0 = Ul[d * 65 + by * 2 + 0];
        float ub1 = Ul[d * 65 + by * 2 + 1];
        float nb0 = Nl[d * 33 + nx * 4 + 0];
        float nb1 = Nl[d * 33 + nx * 4 + 1];
        float nb2 = Nl[d * 33 + nx * 4 + 2];
        float nb3 = Nl[d * 33 + nx * 4 + 3];
        acc[0][0] += ub0 * nb0;  acc[0][1] += ub0 * nb1;
        acc[0][2] += ub0 * nb2;  acc[0][3] += ub0 * nb3;
        acc[1][0] += ub1 * nb0;  acc[1][1] += ub1 * nb1;
        acc[1][2] += ub1 * nb2;  acc[1][3] += ub1 * nb3;
    }

    #pragma unroll
    for (int i = 0; i < 2; ++i) {
        int b = by * 2 + i;
        #pragma unroll
        for (int j = 0; j < 4; ++j) {
            int n = n0 + nx * 4 + j;
            if (n < N_ENTITY)
                out[(size_t)b * N_ENTITY + n] = acc[i][j] + out_bias[n];
        }
    }
}

// ---------------------------------------------------------------------------
extern "C" void kernel_launch(void* const* d_in, const int* in_sizes, int n_in,
                              void* d_out, int out_size, void* d_ws, size_t ws_size,
                              hipStream_t stream)
{
    const int*   seed_ids  = (const int*)d_in[0];
    const int*   esrc      = (const int*)d_in[1];
    const int*   edst      = (const int*)d_in[2];
    const int*   etype     = (const int*)d_in[3];
    const float* basis     = (const float*)d_in[4];
    const float* att       = (const float*)d_in[5];
    const float* root      = (const float*)d_in[6];
    const float* rgcn_bias = (const float*)d_in[7];
    const float* attn_a    = (const float*)d_in[8];
    const float* attn_b    = (const float*)d_in[9];
    const float* out_bias  = (const float*)d_in[10];
    float* out = (float*)d_out;

    float* agg = (float*)d_ws;                         // N_ENTITY*DIM
    float* deg = agg + (size_t)N_ENTITY * DIM;         // N_ENTITY
    float* u   = deg + N_ENTITY;                       // BATCH*DIM

    hipMemsetAsync(agg, 0,
                   ((size_t)N_ENTITY * DIM + N_ENTITY) * sizeof(float), stream);

    edge_scatter<<<(N_EDGES + 3) / 4, 256, 0, stream>>>(
        esrc, edst, etype, basis, att, agg, deg);

    finalize4<<<(N_ENTITY * (DIM / 4) + 255) / 256, 256, 0, stream>>>(
        (float4*)agg, deg, (const float4*)root, (const float4*)rgcn_bias);

    attn_pool<<<BATCH, 256, 0, stream>>>(seed_ids, agg, attn_a, attn_b, u);

    scores_kernel<<<(N_ENTITY + 31) / 32, 256, 0, stream>>>(
        agg, u, out_bias, out);
}

// Round 2
// 713.776 us; speedup vs baseline: 1.2371x; 1.2371x over previous
//
#include <hip/hip_runtime.h>
#include <hip/hip_bf16.h>

#define N_ENTITY 64368
#define N_REL 40
#define DIM 128
#define N_BASES 8
#define N_EDGES 500000
#define BATCH 64
#define SEED_LEN 32
#define NROWS (BATCH * SEED_LEN)            // 2048
#define SCAN_NB ((N_ENTITY + 255) / 256)    // 252

// ===========================================================================
// Counting sort by dst: hist -> 3-phase exclusive scan -> scatter packed meta
// ===========================================================================
__global__ __launch_bounds__(256) void k_hist(
    const int* __restrict__ edst, int* __restrict__ hist)
{
    int e = blockIdx.x * 256 + threadIdx.x;
    if (e < N_EDGES) atomicAdd(&hist[edst[e]], 1);
}

__global__ __launch_bounds__(256) void k_scan1(
    const int* __restrict__ hist, int* __restrict__ ptr,
    int* __restrict__ partial)
{
    __shared__ int s[256];
    int tid = threadIdx.x;
    int gid = blockIdx.x * 256 + tid;
    int v = (gid < N_ENTITY) ? hist[gid] : 0;
    s[tid] = v;
    __syncthreads();
    for (int off = 1; off < 256; off <<= 1) {
        int t = (tid >= off) ? s[tid - off] : 0;
        __syncthreads();
        s[tid] += t;
        __syncthreads();
    }
    if (gid < N_ENTITY) ptr[gid] = s[tid] - v;      // exclusive within block
    if (tid == 255) partial[blockIdx.x] = s[255];   // block total
}

__global__ __launch_bounds__(256) void k_scan2(
    const int* __restrict__ partial, int* __restrict__ poff)
{
    __shared__ int s[256];
    int tid = threadIdx.x;
    int v = (tid < SCAN_NB) ? partial[tid] : 0;
    s[tid] = v;
    __syncthreads();
    for (int off = 1; off < 256; off <<= 1) {
        int t = (tid >= off) ? s[tid - off] : 0;
        __syncthreads();
        s[tid] += t;
        __syncthreads();
    }
    if (tid < SCAN_NB) poff[tid] = s[tid] - v;      // exclusive block offsets
}

__global__ __launch_bounds__(256) void k_scan3(
    int* __restrict__ ptr, const int* __restrict__ poff,
    int* __restrict__ ptr_work)
{
    int gid = blockIdx.x * 256 + threadIdx.x;
    if (gid < N_ENTITY) {
        int p = ptr[gid] + poff[blockIdx.x];
        ptr[gid] = p;
        ptr_work[gid] = p;
    }
}

__global__ __launch_bounds__(256) void k_scatter(
    const int* __restrict__ esrc, const int* __restrict__ edst,
    const int* __restrict__ etype, int* __restrict__ ptr_work,
    int* __restrict__ meta)
{
    int e = blockIdx.x * 256 + threadIdx.x;
    if (e < N_EDGES) {
        int d = edst[e];
        int pos = atomicAdd(&ptr_work[d], 1);
        meta[pos] = esrc[e] * 64 + etype[e];   // pack (src,type), type < 64
    }
}

// ===========================================================================
// Gather: one wave per dst node. Register accumulation, zero atomics,
// fused finalize (agg/deg + root + bias). Writes each node row exactly once.
// ===========================================================================
__global__ __launch_bounds__(256) void k_gather(
    const int* __restrict__ ptr, const int* __restrict__ hist,
    const int* __restrict__ meta, const float* __restrict__ basis,
    const float* __restrict__ att, const float* __restrict__ root,
    const float* __restrict__ bias, float* __restrict__ agg)
{
    __shared__ float att_s[N_REL * N_BASES];
    int tid = threadIdx.x;
    for (int i = tid; i < N_REL * N_BASES; i += 256) att_s[i] = att[i];
    __syncthreads();

    int wid  = (int)((blockIdx.x * 256 + tid) >> 6);
    int lane = tid & 63;
    if (wid >= N_ENTITY) return;

    int p   = ptr[wid];
    int cnt = hist[wid];
    const size_t bstride = (size_t)N_ENTITY * DIM;

    float ax = 0.f, ay = 0.f;

    int j = 0;
    for (; j + 1 < cnt; j += 2) {               // 2 edges in flight
        int m0 = meta[p + j], m1 = meta[p + j + 1];
        int s0 = m0 >> 6, t0 = m0 & 63;
        int s1 = m1 >> 6, t1 = m1 & 63;
        const float* c0 = att_s + t0 * N_BASES;
        const float* c1 = att_s + t1 * N_BASES;
        const float* b0 = basis + (size_t)s0 * DIM + lane * 2;
        const float* b1 = basis + (size_t)s1 * DIM + lane * 2;
        float2 u0 = *(const float2*)(b0 + 0 * bstride);
        float2 u1 = *(const float2*)(b0 + 1 * bstride);
        float2 u2 = *(const float2*)(b0 + 2 * bstride);
        float2 u3 = *(const float2*)(b0 + 3 * bstride);
        float2 u4 = *(const float2*)(b0 + 4 * bstride);
        float2 u5 = *(const float2*)(b0 + 5 * bstride);
        float2 u6 = *(const float2*)(b0 + 6 * bstride);
        float2 u7 = *(const float2*)(b0 + 7 * bstride);
        float2 w0 = *(const float2*)(b1 + 0 * bstride);
        float2 w1 = *(const float2*)(b1 + 1 * bstride);
        float2 w2 = *(const float2*)(b1 + 2 * bstride);
        float2 w3 = *(const float2*)(b1 + 3 * bstride);
        float2 w4 = *(const float2*)(b1 + 4 * bstride);
        float2 w5 = *(const float2*)(b1 + 5 * bstride);
        float2 w6 = *(const float2*)(b1 + 6 * bstride);
        float2 w7 = *(const float2*)(b1 + 7 * bstride);
        ax += c0[0]*u0.x + c0[1]*u1.x + c0[2]*u2.x + c0[3]*u3.x
            + c0[4]*u4.x + c0[5]*u5.x + c0[6]*u6.x + c0[7]*u7.x;
        ay += c0[0]*u0.y + c0[1]*u1.y + c0[2]*u2.y + c0[3]*u3.y
            + c0[4]*u4.y + c0[5]*u5.y + c0[6]*u6.y + c0[7]*u7.y;
        ax += c1[0]*w0.x + c1[1]*w1.x + c1[2]*w2.x + c1[3]*w3.x
            + c1[4]*w4.x + c1[5]*w5.x + c1[6]*w6.x + c1[7]*w7.x;
        ay += c1[0]*w0.y + c1[1]*w1.y + c1[2]*w2.y + c1[3]*w3.y
            + c1[4]*w4.y + c1[5]*w5.y + c1[6]*w6.y + c1[7]*w7.y;
    }
    if (j < cnt) {
        int m0 = meta[p + j];
        int s0 = m0 >> 6, t0 = m0 & 63;
        const float* c0 = att_s + t0 * N_BASES;
        const float* b0 = basis + (size_t)s0 * DIM + lane * 2;
        float2 u0 = *(const float2*)(b0 + 0 * bstride);
        float2 u1 = *(const float2*)(b0 + 1 * bstride);
        float2 u2 = *(const float2*)(b0 + 2 * bstride);
        float2 u3 = *(const float2*)(b0 + 3 * bstride);
        float2 u4 = *(const float2*)(b0 + 4 * bstride);
        float2 u5 = *(const float2*)(b0 + 5 * bstride);
        float2 u6 = *(const float2*)(b0 + 6 * bstride);
        float2 u7 = *(const float2*)(b0 + 7 * bstride);
        ax += c0[0]*u0.x + c0[1]*u1.x + c0[2]*u2.x + c0[3]*u3.x
            + c0[4]*u4.x + c0[5]*u5.x + c0[6]*u6.x + c0[7]*u7.x;
        ay += c0[0]*u0.y + c0[1]*u1.y + c0[2]*u2.y + c0[3]*u3.y
            + c0[4]*u4.y + c0[5]*u5.y + c0[6]*u6.y + c0[7]*u7.y;
    }

    float inv = 1.0f / fmaxf((float)cnt, 1.0f);
    int o = wid * DIM + lane * 2;
    float2 r  = *(const float2*)(root + o);
    float2 bb = *(const float2*)(bias + lane * 2);
    float2 outv;
    outv.x = ax * inv + r.x + bb.x;
    outv.y = ay * inv + r.y + bb.y;
    *(float2*)(agg + o) = outv;
}

// ===========================================================================
// Attention stage 1: T = tanh(H_flat @ A), H_flat rows via seed_ids gather.
// 128 blocks x 16 rows; A staged in LDS (row stride 132, b128-aligned).
// ===========================================================================
__global__ __launch_bounds__(256) void k_attn_gemm(
    const int* __restrict__ seed_ids, const float* __restrict__ nodes,
    const float* __restrict__ A, float* __restrict__ T)
{
    __shared__ float As[DIM * 132];       // [d][j], stride 132 (16B aligned)
    __shared__ float Hs[16 * DIM];        // 16 rows

    int tid = threadIdx.x;
    int r0  = blockIdx.x * 16;

    for (int i = tid; i < DIM * DIM; i += 256) {
        int row = i >> 7, col = i & 127;
        As[row * 132 + col] = A[i];       // coalesced read, conflict-free write
    }
    for (int i = tid; i < 16 * DIM; i += 256) {
        int rr = i >> 7, d = i & 127;
        int nid = seed_ids[r0 + rr];
        Hs[rr * DIM + d] = nodes[(size_t)nid * DIM + d];
    }
    __syncthreads();

    int jx = tid & 31;        // 32 groups x 4 cols
    int iy = tid >> 5;        // 8 groups x 2 rows
    float acc[2][4] = {{0,0,0,0},{0,0,0,0}};

    for (int d = 0; d < DIM; ++d) {
        float h0 = Hs[(iy * 2 + 0) * DIM + d];    // broadcast
        float h1 = Hs[(iy * 2 + 1) * DIM + d];
        const float4 a4 = *(const float4*)(As + d * 132 + jx * 4);
        acc[0][0] += h0 * a4.x; acc[0][1] += h0 * a4.y;
        acc[0][2] += h0 * a4.z; acc[0][3] += h0 * a4.w;
        acc[1][0] += h1 * a4.x; acc[1][1] += h1 * a4.y;
        acc[1][2] += h1 * a4.z; acc[1][3] += h1 * a4.w;
    }
    #pragma unroll
    for (int i = 0; i < 2; ++i) {
        int r = r0 + iy * 2 + i;
        #pragma unroll
        for (int k = 0; k < 4; ++k)
            T[(size_t)r * DIM + jx * 4 + k] = tanhf(acc[i][k]);
    }
}

// ===========================================================================
// Attention stage 2: e = T@b, per-batch softmax over 32, u = attn@H.
// Writes u [B][D] and its transpose uT [D][B] (for the scores kernel).
// ===========================================================================
__global__ __launch_bounds__(256) void k_attn_pool(
    const int* __restrict__ seed_ids, const float* __restrict__ nodes,
    const float* __restrict__ T, const float* __restrict__ Bv,
    float* __restrict__ u, float* __restrict__ uT)
{
    __shared__ float part[SEED_LEN][9];
    __shared__ float attw[SEED_LEN];

    int b = blockIdx.x, tid = threadIdx.x;
    int s = tid >> 3, g = tid & 7;

    float pe = 0.0f;
    for (int jj = g; jj < DIM; jj += 8)
        pe += T[(size_t)(b * SEED_LEN + s) * DIM + jj] * Bv[jj];
    part[s][g] = pe;
    __syncthreads();

    if (tid < SEED_LEN) {
        float e = 0.0f;
        for (int k = 0; k < 8; ++k) e += part[tid][k];
        attw[tid] = e;
    }
    __syncthreads();

    if (tid == 0) {
        float mx = -1e30f;
        for (int k = 0; k < SEED_LEN; ++k) mx = fmaxf(mx, attw[k]);
        float ssum = 0.0f;
        for (int k = 0; k < SEED_LEN; ++k) {
            float v = expf(attw[k] - mx);
            attw[k] = v; ssum += v;
        }
        float inv = 1.0f / ssum;
        for (int k = 0; k < SEED_LEN; ++k) attw[k] *= inv;
    }
    __syncthreads();

    if (tid < DIM) {
        float acc = 0.0f;
        for (int k = 0; k < SEED_LEN; ++k) {
            int nid = seed_ids[b * SEED_LEN + k];
            acc += attw[k] * nodes[(size_t)nid * DIM + tid];
        }
        u[b * DIM + tid]  = acc;
        uT[tid * BATCH + b] = acc;
    }
}

// ===========================================================================
// Scores: out[b][n] = u[b]·nodes[n] + out_bias[n].
// Block = 64 batches x 64 nodes; wave w owns b in [w*16, w*16+16), lane = n.
// nodes staged in LDS (stride 65, conflict-free); u read wave-uniform from
// uT via readfirstlane -> scalar loads. 1 ds_read_b32 per 16 FMAs.
// ===========================================================================
__global__ __launch_bounds__(256) void k_scores(
    const float* __restrict__ nodes, const float* __restrict__ uT,
    const float* __restrict__ out_bias, float* __restrict__ out)
{
    __shared__ float Nl[DIM * 65];   // [d][n], stride 65

    int tid = threadIdx.x;
    int n0  = blockIdx.x * 64;

    for (int i = tid; i < 64 * DIM; i += 256) {
        int n = i >> 7, d = i & 127;                 // flat = n*128+d: coalesced
        int gn = n0 + n;
        Nl[d * 65 + n] = (gn < N_ENTITY) ? nodes[(size_t)gn * DIM + d] : 0.0f;
    }
    __syncthreads();

    int w    = __builtin_amdgcn_readfirstlane(tid >> 6);  // wave id, uniform
    int lane = tid & 63;
    int b0   = w * 16;

    float acc[16];
    #pragma unroll
    for (int k = 0; k < 16; ++k) acc[k] = 0.0f;

    #pragma unroll 4
    for (int d = 0; d < DIM; ++d) {
        float nv = Nl[d * 65 + lane];
        const float* up = uT + d * BATCH + b0;       // uniform -> s_load
        #pragma unroll
        for (int k = 0; k < 16; ++k) acc[k] += up[k] * nv;
    }

    int gn = n0 + lane;
    if (gn < N_ENTITY) {
        float ob = out_bias[gn];
        #pragma unroll
        for (int k = 0; k < 16; ++k)
            out[(size_t)(b0 + k) * N_ENTITY + gn] = acc[k] + ob;
    }
}

// ===========================================================================
extern "C" void kernel_launch(void* const* d_in, const int* in_sizes, int n_in,
                              void* d_out, int out_size, void* d_ws, size_t ws_size,
                              hipStream_t stream)
{
    const int*   seed_ids  = (const int*)d_in[0];
    const int*   esrc      = (const int*)d_in[1];
    const int*   edst      = (const int*)d_in[2];
    const int*   etype     = (const int*)d_in[3];
    const float* basis     = (const float*)d_in[4];
    const float* att       = (const float*)d_in[5];
    const float* root      = (const float*)d_in[6];
    const float* rgcn_bias = (const float*)d_in[7];
    const float* attn_a    = (const float*)d_in[8];
    const float* attn_b    = (const float*)d_in[9];
    const float* out_bias  = (const float*)d_in[10];
    float* out = (float*)d_out;

    // workspace layout (floats/ints, 4B units) — ~36.9 MB total
    float* agg      = (float*)d_ws;                          // 8,239,104
    int*   hist     = (int*)(agg + (size_t)N_ENTITY * DIM);  // 64,368
    int*   ptr      = hist + N_ENTITY;                       // 64,368
    int*   ptr_work = ptr + N_ENTITY;                        // 64,368
    int*   partial  = ptr_work + N_ENTITY;                   // 256
    int*   poff     = partial + 256;                         // 256
    int*   meta     = poff + 256;                            // 500,000
    float* T        = (float*)(meta + N_EDGES);              // 262,144
    float* u        = T + (size_t)NROWS * DIM;               // 8,192
    float* uT       = u + BATCH * DIM;                       // 8,192

    hipMemsetAsync(hist, 0, N_ENTITY * sizeof(int), stream);

    k_hist<<<(N_EDGES + 255) / 256, 256, 0, stream>>>(edst, hist);
    k_scan1<<<SCAN_NB, 256, 0, stream>>>(hist, ptr, partial);
    k_scan2<<<1, 256, 0, stream>>>(partial, poff);
    k_scan3<<<SCAN_NB, 256, 0, stream>>>(ptr, poff, ptr_work);
    k_scatter<<<(N_EDGES + 255) / 256, 256, 0, stream>>>(
        esrc, edst, etype, ptr_work, meta);

    k_gather<<<(N_ENTITY * 64 + 255) / 256, 256, 0, stream>>>(
        ptr, hist, meta, basis, att, root, rgcn_bias, agg);

    k_attn_gemm<<<NROWS / 16, 256, 0, stream>>>(seed_ids, agg, attn_a, T);
    k_attn_pool<<<BATCH, 256, 0, stream>>>(seed_ids, agg, T, attn_b, u, uT);

    k_scores<<<(N_ENTITY + 63) / 64, 256, 0, stream>>>(agg, uT, out_bias, out);
}